// Round 6
// baseline (124.157 us; speedup 1.0000x reference)
//
#include <hip/hip_runtime.h>
#include <hip/hip_bf16.h>

typedef __attribute__((ext_vector_type(8))) short bf16x8;
typedef __attribute__((ext_vector_type(4))) short s16x4;
typedef __attribute__((ext_vector_type(4))) float f32x4;

__device__ __forceinline__ short f2b(float f) {
    __hip_bfloat16 h = __float2bfloat16(f);   // RNE
    return __builtin_bit_cast(short, h);
}

#define KT 512      // K-tile in floats (2 KB/row f32, 1 KB/row bf16 in LDS)
#define NT 8        // 4096 / 512

// Kernel 1: x f32 -> bf16, and y2 = 2*(x @ A^T) as bf16.
__global__ void prep_kernel(const float* __restrict__ x,
                            const float* __restrict__ A,
                            ushort* __restrict__ xb,     // [64][4096] bf16
                            ushort* __restrict__ yb) {   // [64][64] bf16
    const int tid = threadIdx.x, bid = blockIdx.x;

    const int gid = bid * 256 + tid;
    if (gid < 65536) {
        float4 v = ((const float4*)x)[gid];
        ushort4 s;
        s.x = (ushort)f2b(v.x); s.y = (ushort)f2b(v.y);
        s.z = (ushort)f2b(v.z); s.w = (ushort)f2b(v.w);
        ((ushort4*)xb)[gid] = s;
    }

    const int wave = tid >> 6, lane = tid & 63;
    const int idx = bid * 4 + wave;          // 0..4095
    const int t = idx >> 6, r = idx & 63;
    const float4* xr = (const float4*)(x + (size_t)t * 4096);
    const float4* ar = (const float4*)(A + (size_t)r * 4096);
    float s = 0.f;
    #pragma unroll
    for (int i = 0; i < 16; ++i) {
        float4 a = xr[i * 64 + lane];
        float4 b = ar[i * 64 + lane];
        s += a.x * b.x + a.y * b.y + a.z * b.z + a.w * b.w;
    }
    #pragma unroll
    for (int off = 32; off; off >>= 1) s += __shfl_xor(s, off, 64);
    if (lane == 0) yb[idx] = (ushort)f2b(2.0f * s);
}

// Kernel 2: out[64][16384] = x@W^T + y2@B^T.
// 1024 blocks x 256 threads. Block owns W rows j0..j0+15 (contiguous 256 KB).
// T3+T4 schedule: raw s_barrier + lgkmcnt(0) only (NO __syncthreads -> no
// vmcnt(0) drain in the main loop); W loads prefetched DISTANCE 2 in two
// static register banks, so ~2 compute phases of latency cover and loads
// stay in flight across barriers (counted vmcnt on the older bank only).
__global__ void __launch_bounds__(256, 4)
lora_gemm(const float* __restrict__ W,      // [16384][4096]
          const float* __restrict__ Bm,     // [16384][64]
          const ushort* __restrict__ xb,    // [64][4096] bf16
          const ushort* __restrict__ yb,    // [64][64] bf16
          float* __restrict__ out) {        // [64][16384]
    __shared__ ushort lds[2][16 * KT];      // 2 x 16 KB (bf16)

    const int tid  = threadIdx.x;
    const int w    = tid >> 6;              // wave 0..3 -> token group
    const int lane = tid & 63;
    const int c    = lane & 15;             // frag row/col index
    const int kg   = lane >> 4;             // k-group, offset kg*8
    const int j0   = blockIdx.x << 4;
    const int sx   = (c & 7) << 4;          // read-side swizzle

    const ushort* xrow = xb + (size_t)(w * 16 + c) * 4096 + kg * 8;

    f32x4 rgA[4][2], rgB[4][2];             // two static prefetch banks

    #define LOAD_T(rg, t)                                                  \
        { _Pragma("unroll")                                                \
          for (int q = 0; q < 4; ++q) {                                    \
              const float* src = W + (size_t)(j0 + w * 4 + q) * 4096       \
                                   + (size_t)(t) * KT + lane * 4;          \
              rg[q][0] = *(const f32x4*)(src);                             \
              rg[q][1] = *(const f32x4*)(src + 256);                       \
          } }

    // cvt f32->bf16, ds_write XOR-swizzled (write-side swizzle: reg-staged)
    #define WRITE_T(rg, buf)                                               \
        { _Pragma("unroll")                                                \
          for (int q = 0; q < 4; ++q) {                                    \
              const int r_ = w * 4 + q;                                    \
              char* rowb = (char*)&lds[buf][0] + r_ * 1024;                \
              _Pragma("unroll")                                            \
              for (int h = 0; h < 2; ++h) {                                \
                  s16x4 p;                                                 \
                  p[0] = f2b(rg[q][h][0]); p[1] = f2b(rg[q][h][1]);        \
                  p[2] = f2b(rg[q][h][2]); p[3] = f2b(rg[q][h][3]);        \
                  *(s16x4*)(rowb + ((h * 512 + lane * 8)                   \
                                    ^ ((r_ & 7) << 4))) = p;               \
              } } }

    #define COMPUTE_T(buf, t)                                              \
        { const char* lrow = (const char*)&lds[buf][0] + c * 1024;         \
          _Pragma("unroll")                                                \
          for (int s = 0; s < 16; ++s) {                                   \
              bf16x8 bb = *(const bf16x8*)(lrow + ((s * 64 + kg * 16) ^ sx)); \
              bf16x8 aa = *(const bf16x8*)(xrow + (size_t)(t) * KT + s * 32); \
              acc = __builtin_amdgcn_mfma_f32_16x16x32_bf16(aa, bb, acc, 0, 0, 0); \
          } }

    #define LGKM_BARRIER()                                                 \
        asm volatile("s_waitcnt lgkmcnt(0)" ::: "memory");                 \
        __builtin_amdgcn_s_barrier();                                      \
        __builtin_amdgcn_sched_barrier(0);

    f32x4 acc = {0.f, 0.f, 0.f, 0.f};

    // prologue: tile0 -> buf0 (one full-latency stall, amortized),
    // tile1 loads left in flight in rgB.
    LOAD_T(rgA, 0);
    WRITE_T(rgA, 0);
    LOAD_T(rgB, 1);
    LGKM_BARRIER();

    #pragma unroll
    for (int t = 0; t < NT; t += 2) {
        if (t + 2 < NT) LOAD_T(rgA, t + 2);   // in flight ~2 phases
        COMPUTE_T(0, t);
        WRITE_T(rgB, 1);                      // counted vmcnt on rgB only
        LGKM_BARRIER();

        if (t + 3 < NT) LOAD_T(rgB, t + 3);
        COMPUTE_T(1, t + 1);
        if (t + 2 < NT) {
            WRITE_T(rgA, 0);
            LGKM_BARRIER();
        }
    }

    #undef LOAD_T
    #undef WRITE_T
    #undef COMPUTE_T
    #undef LGKM_BARRIER

    // lora tail: 2 K-steps over r=64 with B matrix and y2
    {
        const float*  br = Bm + (size_t)(j0 + c) * 64 + kg * 8;
        const ushort* y0 = yb + (size_t)(w * 16 + c) * 64 + kg * 8;
        #pragma unroll
        for (int k = 0; k < 64; k += 32) {
            f32x4 w0 = *(const f32x4*)(br + k);
            f32x4 w1 = *(const f32x4*)(br + k + 4);
            bf16x8 bb;
            bb[0] = f2b(w0[0]); bb[1] = f2b(w0[1]);
            bb[2] = f2b(w0[2]); bb[3] = f2b(w0[3]);
            bb[4] = f2b(w1[0]); bb[5] = f2b(w1[1]);
            bb[6] = f2b(w1[2]); bb[7] = f2b(w1[3]);
            bf16x8 aa = *(const bf16x8*)(y0 + k);
            acc = __builtin_amdgcn_mfma_f32_16x16x32_bf16(aa, bb, acc, 0, 0, 0);
        }
    }

    // store: token row = w*16 + kg*4 + r, col = j0 + c
    float* op = out + j0 + c;
    #pragma unroll
    for (int r = 0; r < 4; ++r)
        op[(size_t)(w * 16 + kg * 4 + r) * 16384] = acc[r];
}

extern "C" void kernel_launch(void* const* d_in, const int* in_sizes, int n_in,
                              void* d_out, int out_size, void* d_ws, size_t ws_size,
                              hipStream_t stream) {
    const float* x  = (const float*)d_in[0];
    const float* W  = (const float*)d_in[1];
    const float* A  = (const float*)d_in[2];
    const float* Bm = (const float*)d_in[3];
    float* out = (float*)d_out;

    ushort* xb = (ushort*)d_ws;                          // 64*4096*2 = 524288 B
    ushort* yb = (ushort*)((char*)d_ws + 524288);        // 64*64*2   = 8192 B

    prep_kernel<<<1024, 256, 0, stream>>>(x, A, xb, yb);
    lora_gemm<<<1024, 256, 0, stream>>>(W, Bm, xb, yb, out);
}